// Round 7
// baseline (508.484 us; speedup 1.0000x reference)
//
#include <hip/hip_runtime.h>

typedef _Float16 half8 __attribute__((ext_vector_type(8)));
typedef _Float16 half4v __attribute__((ext_vector_type(4)));
typedef float floatx4 __attribute__((ext_vector_type(4)));

#define AS3 __attribute__((address_space(3)))
#define AS1 __attribute__((address_space(1)))

// async global->LDS, 16B per lane, wave-uniform LDS base + lane*16
__device__ __forceinline__ void gload_lds16(const _Float16* g, _Float16* l) {
    __builtin_amdgcn_global_load_lds((AS1 void*)g, (AS3 void*)l, 16, 0, 0);
}

__device__ __forceinline__ floatx4 mfma16(half8 a, half8 b, floatx4 c) {
    return __builtin_amdgcn_mfma_f32_16x16x32_f16(a, b, c, 0, 0, 0);
}

// ---------------- fused f32 -> f16 convert of all three inputs ----------------
// Separate pass is REQUIRED: fusing cvt into GEMM staging (R6) re-reads f32
// sources once per re-used panel -> 105MB fetch, MfmaUtil 19%, +35us. One
// pass amortizes conversion once (52MB read + 26MB write, ~16us).
__global__ __launch_bounds__(256) void cvt_all(const float* __restrict__ x,
                                               const float* __restrict__ wq,
                                               const float* __restrict__ wp,
                                               _Float16* __restrict__ xh,
                                               _Float16* __restrict__ wqh,
                                               _Float16* __restrict__ wph) {
    long i = (long)blockIdx.x * 256 + threadIdx.x;   // float4 index
    const float4* src; half4v* dst; long off;
    if (i < 2097152)      { src = (const float4*)x;  dst = (half4v*)xh;  off = i; }
    else if (i < 2883584) { src = (const float4*)wq; dst = (half4v*)wqh; off = i - 2097152; }
    else                  { src = (const float4*)wp; dst = (half4v*)wph; off = i - 2883584; }
    float4 v = src[off];
    half4v h = {(_Float16)v.x, (_Float16)v.y, (_Float16)v.z, (_Float16)v.w};
    dst[off] = h;
}

// ---------------- TN GEMM (QKV): reg-staged pipeline, 5 blocks/CU -----------
// C[M,N] = A[M,K] * B[N,K]^T. 128x128 tile, BK=32, 256 threads, dbuf LDS.
// Best-measured structure (71-73us): global->VGPR right after barrier,
// compute from LDS, ds_write regs -> other buffer (vmcnt wait lands one
// compute phase after issue).  All alternative schedules were neutral/worse:
// gload_lds 74.6 (R1), 8-phase 256² 82.8 (R3), 256x128 triple-buf 76.9 (R4),
// fused-cvt 107+ (R6).
// R12 change: __launch_bounds__(256,5) — LDS 32KB allows 5 blocks/CU (160KB),
// VGPR 64 << 102-per-wave budget at 5 waves/EU.  The stall signature
// (MfmaUtil 28 + VALU 16 + 0 conflicts => ~50% barrier-wait) is fillable by
// one more independent resident block per CU.
// LDS swizzle: chunk c of row r -> slot c ^ ((r>>1)&3) (involution; verified
// SQ_LDS_BANK_CONFLICT = 0).
template<bool DUMMY>
__global__ __launch_bounds__(256, 5) void gemm_tn(
    const _Float16* __restrict__ A, const _Float16* __restrict__ B,
    _Float16* __restrict__ Ch, int ldc, _Float16* __restrict__ Vt, int split,
    float* __restrict__ Cf, const float* __restrict__ bias,
    int M, int Nn, int K)
{
    __shared__ _Float16 sA[2][128 * 32];
    __shared__ _Float16 sB[2][128 * 32];
    const int tid  = threadIdx.x;
    const int lane = tid & 63, wave = tid >> 6;
    const int quad = lane >> 4, l16 = lane & 15;
    const int wr = wave >> 1, wc = wave & 1;
    const long m0 = (long)blockIdx.x * 128, n0 = (long)blockIdx.y * 128;

    // thread tid owns row srow (and srow+64), 16B chunk (tid&3) of the 64B k-row.
    const int srow = tid >> 2;
    const int sslot = ((tid & 3) ^ ((srow >> 1) & 3)) * 8;
    const int dlo = srow * 32 + sslot;
    const int dhi = (srow + 64) * 32 + sslot;
    const _Float16* gA0 = A + (m0 + srow) * (long)K + (tid & 3) * 8;
    const _Float16* gA1 = A + (m0 + srow + 64) * (long)K + (tid & 3) * 8;
    const _Float16* gB0 = B + (n0 + srow) * (long)K + (tid & 3) * 8;
    const _Float16* gB1 = B + (n0 + srow + 64) * (long)K + (tid & 3) * 8;

    const int swz = (l16 >> 1) & 3;
    const int aoff = ((quad ^ swz) * 8);

    floatx4 acc[4][4] = {};
    const int nk = K >> 5;

    // prologue: tile 0 -> VGPR -> LDS buf 0
    half8 rA0 = *(const half8*)gA0, rA1 = *(const half8*)gA1;
    half8 rB0 = *(const half8*)gB0, rB1 = *(const half8*)gB1;
    *(half8*)&sA[0][dlo] = rA0; *(half8*)&sA[0][dhi] = rA1;
    *(half8*)&sB[0][dlo] = rB0; *(half8*)&sB[0][dhi] = rB1;

    for (int kk = 0; kk < nk; kk++) {
        const int cur = kk & 1;
        __syncthreads();               // lgkm drain only; vmcnt already 0 here
        const bool more = (kk + 1 < nk);
        if (more) {
            const long k0 = (long)(kk + 1) << 5;
            rA0 = *(const half8*)(gA0 + k0); rA1 = *(const half8*)(gA1 + k0);
            rB0 = *(const half8*)(gB0 + k0); rB1 = *(const half8*)(gB1 + k0);
        }

        const _Float16* cA = &sA[cur][0];
        const _Float16* cB = &sB[cur][0];
        half8 af[4], bf[4];
#pragma unroll
        for (int t = 0; t < 4; t++)
            af[t] = *(const half8*)&cA[(wr * 64 + t * 16 + l16) * 32 + aoff];
#pragma unroll
        for (int t = 0; t < 4; t++)
            bf[t] = *(const half8*)&cB[(wc * 64 + t * 16 + l16) * 32 + aoff];
#pragma unroll
        for (int tm = 0; tm < 4; tm++)
#pragma unroll
            for (int tn = 0; tn < 4; tn++)
                acc[tm][tn] = mfma16(af[tm], bf[tn], acc[tm][tn]);

        if (more) {
            _Float16* nA = &sA[cur ^ 1][0];
            _Float16* nB = &sB[cur ^ 1][0];
            *(half8*)&nA[dlo] = rA0; *(half8*)&nA[dhi] = rA1;   // vmcnt wait lands here,
            *(half8*)&nB[dlo] = rB0; *(half8*)&nB[dhi] = rB1;   // one compute phase after issue
        }
    }

    // epilogue: C/D layout col=lane&15, row=quad*4+reg (verified m89/m91)
#pragma unroll
    for (int tm = 0; tm < 4; tm++) {
        long row = m0 + wr * 64 + tm * 16 + quad * 4;
#pragma unroll
        for (int tn = 0; tn < 4; tn++) {
            long col = n0 + wc * 64 + tn * 16 + l16;
            if (Cf) {
                float bv = bias ? bias[col] : 0.f;
#pragma unroll
                for (int r = 0; r < 4; r++)
                    Cf[(row + r) * (long)Nn + col] = acc[tm][tn][r] + bv;
            } else if (col >= split) {
                // transposed V write: Vt[(b*16+h)*64+d][n], n = 4 consecutive rows
                long cv = col - split;
                long vrow = ((row >> 10) * 16 + (cv >> 6)) * 64 + (cv & 63);
                long nn = row & 1023;
                half4v pv = {(_Float16)acc[tm][tn][0], (_Float16)acc[tm][tn][1],
                             (_Float16)acc[tm][tn][2], (_Float16)acc[tm][tn][3]};
                *(half4v*)&Vt[vrow * 1024 + nn] = pv;
            } else {
#pragma unroll
                for (int r = 0; r < 4; r++)
                    Ch[(row + r) * (long)ldc + col] = (_Float16)acc[tm][tn][r];
            }
        }
    }
}

// ---------------- 256x128 triple-buffered counted-vmcnt TN GEMM (proj) ------
// Kept ONLY for proj: grid 32x8 = 256 blocks = exactly 1 generation @ 1
// block/CU -> ~25-28us (vs gemm_tn's ~34 at 512 blocks).
__global__ __launch_bounds__(512, 2) void gemm256(
    const _Float16* __restrict__ A, const _Float16* __restrict__ B,
    _Float16* __restrict__ Ch, int ldc, _Float16* __restrict__ Vt, int split,
    float* __restrict__ Cf, const float* __restrict__ bias, int Nn, int K)
{
    __shared__ _Float16 sAB[3 * 24576];   // [buf][ A:16384 | B:8192 ] halfs

    const int nwg = gridDim.x * gridDim.y;
    int bid = blockIdx.y * gridDim.x + blockIdx.x;
    const int cpx = nwg >> 3;
    bid = (bid & 7) * cpx + (bid >> 3);
    const int gsz = gridDim.y << 3;
    const int bxg = bid / gsz;
    const int rem = bid - bxg * gsz;
    const int by = rem >> 3;
    const int bx = (bxg << 3) + (rem & 7);

    const int tid = threadIdx.x;
    const int lane = tid & 63, wave = tid >> 6;
    const int quad = lane >> 4, l16 = lane & 15;
    const int wm = wave >> 1, wn = wave & 1;      // 4M x 2N wave grid
    const long m0 = (long)bx * 256, n0 = (long)by * 128;

    const int gch = ((tid & 7) ^ ((tid >> 3) & 7)) * 8;
    const _Float16* gA = A + (m0 + (tid >> 3)) * (long)K + gch;
    const _Float16* gB = B + (n0 + (tid >> 3)) * (long)K + gch;
    const int wst = wave * 512;

#define STAGE(sb, u) do {                                                     \
    const long ko = (long)(u) * 64;                                           \
    _Float16* d = &sAB[(sb) * 24576];                                         \
    gload_lds16(gA + ko,                 d + wst);                            \
    gload_lds16(gA +  64 * (long)K + ko, d + 4096  + wst);                    \
    gload_lds16(gA + 128 * (long)K + ko, d + 8192  + wst);                    \
    gload_lds16(gA + 192 * (long)K + ko, d + 12288 + wst);                    \
    gload_lds16(gB + ko,                 d + 16384 + wst);                    \
    gload_lds16(gB +  64 * (long)K + ko, d + 20480 + wst);                    \
} while (0)

    const int NT = K >> 6;
    STAGE(0, 0); STAGE(1, 1);
    asm volatile("s_waitcnt vmcnt(6)" ::: "memory");   // tile 0 resident
    __builtin_amdgcn_s_barrier();

    const int cs0 = (quad ^ (l16 & 7)) * 8;         // ks=0 swizzled chunk
    const int cs1 = ((4 + quad) ^ (l16 & 7)) * 8;   // ks=1

    floatx4 acc[4][4] = {};
    half8 afr[4][2], bf0[2][2], bf1[2][2];

    int cb = 0, sb = 2;   // cur buf = t%3, stage buf = (t+2)%3
    for (int t = 0; t < NT; ++t) {
        const _Float16* cA = &sAB[cb * 24576 + wm * 4096];
        const _Float16* cB = &sAB[cb * 24576 + 16384 + wn * 4096];

#pragma unroll
        for (int f = 0; f < 4; f++) {
            const _Float16* p = &cA[(f * 16 + l16) * 64];
            afr[f][0] = *(const half8*)&p[cs0];
            afr[f][1] = *(const half8*)&p[cs1];
        }
#pragma unroll
        for (int nf = 0; nf < 2; nf++) {
            const _Float16* p = &cB[(nf * 16 + l16) * 64];
            bf0[nf][0] = *(const half8*)&p[cs0];
            bf0[nf][1] = *(const half8*)&p[cs1];
        }
        if (t + 2 < NT) STAGE(sb, t + 2);
        __builtin_amdgcn_s_barrier();
        asm volatile("s_waitcnt lgkmcnt(0)" ::: "memory");
        __builtin_amdgcn_sched_barrier(0);
        __builtin_amdgcn_s_setprio(1);
#pragma unroll
        for (int f = 0; f < 4; f++)
#pragma unroll
            for (int nf = 0; nf < 2; nf++) {
                acc[f][nf] = mfma16(afr[f][0], bf0[nf][0], acc[f][nf]);
                acc[f][nf] = mfma16(afr[f][1], bf0[nf][1], acc[f][nf]);
            }
        __builtin_amdgcn_s_setprio(0);
        __builtin_amdgcn_s_barrier();

#pragma unroll
        for (int nf = 0; nf < 2; nf++) {
            const _Float16* p = &cB[((2 + nf) * 16 + l16) * 64];
            bf1[nf][0] = *(const half8*)&p[cs0];
            bf1[nf][1] = *(const half8*)&p[cs1];
        }
        __builtin_amdgcn_s_barrier();
        asm volatile("s_waitcnt lgkmcnt(0)" ::: "memory");
        __builtin_amdgcn_sched_barrier(0);
        __builtin_amdgcn_s_setprio(1);
#pragma unroll
        for (int f = 0; f < 4; f++)
#pragma unroll
            for (int nf = 0; nf < 2; nf++) {
                acc[f][2 + nf] = mfma16(afr[f][0], bf1[nf][0], acc[f][2 + nf]);
                acc[f][2 + nf] = mfma16(afr[f][1], bf1[nf][1], acc[f][2 + nf]);
            }
        __builtin_amdgcn_s_setprio(0);
        if (t + 2 < NT)       { asm volatile("s_waitcnt vmcnt(6)" ::: "memory"); }
        else if (t == NT - 2) { asm volatile("s_waitcnt vmcnt(0)" ::: "memory"); }
        __builtin_amdgcn_s_barrier();
        cb = (cb + 1 == 3) ? 0 : cb + 1;
        sb = (sb + 1 == 3) ? 0 : sb + 1;
    }
#undef STAGE

#pragma unroll
    for (int f = 0; f < 4; f++) {
        long row = m0 + wm * 64 + f * 16 + quad * 4;
#pragma unroll
        for (int cn = 0; cn < 4; cn++) {
            long col = n0 + wn * 64 + cn * 16 + l16;
            if (Cf) {
                float bv = bias ? bias[col] : 0.f;
#pragma unroll
                for (int r = 0; r < 4; r++)
                    Cf[(row + r) * (long)Nn + col] = acc[f][cn][r] + bv;
            } else if (col >= split) {
                long cv = col - split;
                long vrow = ((row >> 10) * 16 + (cv >> 6)) * 64 + (cv & 63);
                long nn = row & 1023;
                half4v pv = {(_Float16)acc[f][cn][0], (_Float16)acc[f][cn][1],
                             (_Float16)acc[f][cn][2], (_Float16)acc[f][cn][3]};
                *(half4v*)&Vt[vrow * 1024 + nn] = pv;
            } else {
#pragma unroll
                for (int r = 0; r < 4; r++)
                    Ch[(row + r) * (long)ldc + col] = (_Float16)acc[f][cn][r];
            }
        }
    }
}

// ---------------- flash attention (S^T orientation) ----------------
// T14 async-STAGE split (K/V tile kt+1 global->reg issued right after tile
// kt's LDS stores; vmcnt wait lands at next iter's ds_write, one compute
// phase later) + T13 defer-max (skip O/l rescale while tile max growth <= 8;
// P bounded by e^8, f16-safe) + SCALE folded into Q at load (0.125 = 2^-3,
// exact in f16).
__global__ __launch_bounds__(256, 4) void flash_attn(const _Float16* __restrict__ qk,
                                                     const _Float16* __restrict__ vt,
                                                     _Float16* __restrict__ out)
{
    const int bh = blockIdx.x, b = bh >> 4, h = bh & 15;
    const int n0 = blockIdx.y * 128;
    const int tid = threadIdx.x, lane = tid & 63, wave = tid >> 6;
    const int quad = lane >> 4, l16 = lane & 15;

    __shared__ _Float16 sK[64 * 72];        // [kr][d] pad 72
    __shared__ _Float16 sVT[64 * 72];       // [d][kr] pad 72
    __shared__ _Float16 sPT[4][32 * 72];    // per-wave P^T round-trip [q][kr], reused as sOut

    half8 qf[2][2];
    const _Float16* qbase = qk + (long)(b * 1024 + n0 + wave * 32) * 2048 + h * 64;
#pragma unroll
    for (int t = 0; t < 2; t++)
#pragma unroll
        for (int s = 0; s < 2; s++) {
            half8 v = *(const half8*)(qbase + (long)(t * 16 + l16) * 2048 + s * 32 + quad * 8);
#pragma unroll
            for (int j = 0; j < 8; j++) v[j] *= (_Float16)0.125f;   // exact pow2
            qf[t][s] = v;
        }

    const int srow = tid >> 3, scol8 = (tid & 7) * 8;
    const _Float16* kgb = qk + 1024 + h * 64 + scol8 + (long)(b * 1024 + srow) * 2048;
    const _Float16* vgb = vt + (long)(bh * 64 + srow) * 1024 + scol8;

    float m_[2] = {-1e30f, -1e30f}, l_[2] = {0.f, 0.f};
    floatx4 o[2][4] = {};

    // T14 prologue: tile 0 -> regs
    half8 rK0 = *(const half8*)(kgb);
    half8 rK1 = *(const half8*)(kgb + (long)32 * 2048);
    half8 rV0 = *(const half8*)(vgb);
    half8 rV1 = *(const half8*)(vgb + (long)32 * 1024);

    for (int kt = 0; kt < 16; kt++) {
        __syncthreads();                       // prev tile's LDS readers done
        *(half8*)&sK[srow * 72 + scol8]          = rK0;
        *(half8*)&sK[(srow + 32) * 72 + scol8]   = rK1;
        *(half8*)&sVT[srow * 72 + scol8]         = rV0;
        *(half8*)&sVT[(srow + 32) * 72 + scol8]  = rV1;
        __syncthreads();

        if (kt + 1 < 16) {                     // issue kt+1 loads; waited at
            const long kr0n = (long)(kt + 1) * 64;          // next iter's stores
            rK0 = *(const half8*)(kgb + kr0n * 2048);
            rK1 = *(const half8*)(kgb + (kr0n + 32) * 2048);
            rV0 = *(const half8*)(vgb + kr0n);
            rV1 = *(const half8*)(vgb + (long)32 * 1024 + kr0n);
        }

        // S^T = K Q^T: A=K (m=kr), B=Q (n=q). C-layout: kr=c*16+quad*4+r, q=t*16+l16
        floatx4 sacc[2][4] = {};
#pragma unroll
        for (int c = 0; c < 4; c++)
#pragma unroll
            for (int s = 0; s < 2; s++) {
                half8 kf = *(const half8*)&sK[(c * 16 + l16) * 72 + s * 32 + quad * 8];
                sacc[0][c] = mfma16(kf, qf[0][s], sacc[0][c]);
                sacc[1][c] = mfma16(kf, qf[1][s], sacc[1][c]);
            }

        // online softmax over kr: in-lane reduce + 2 shuffles (xor16, xor32)
#pragma unroll
        for (int t = 0; t < 2; t++) {
            float mx = -1e30f;
#pragma unroll
            for (int c = 0; c < 4; c++)
#pragma unroll
                for (int r = 0; r < 4; r++)
                    mx = fmaxf(mx, sacc[t][c][r]);
            mx = fmaxf(mx, __shfl_xor(mx, 16));
            mx = fmaxf(mx, __shfl_xor(mx, 32));
            // T13 defer-max: only rescale when max grew past threshold
            if (__any(mx > m_[t] + 8.f)) {
                float mn = fmaxf(m_[t], mx);
                float al = __expf(m_[t] - mn);
                m_[t] = mn;
                l_[t] *= al;
#pragma unroll
                for (int dt = 0; dt < 4; dt++) o[t][dt] *= al;
            }
            float rs = 0.f;
#pragma unroll
            for (int c = 0; c < 4; c++)
#pragma unroll
                for (int r = 0; r < 4; r++) {
                    float p = __expf(sacc[t][c][r] - m_[t]);
                    sacc[t][c][r] = p;
                    rs += p;
                }
            rs += __shfl_xor(rs, 16);
            rs += __shfl_xor(rs, 32);
            l_[t] += rs;
            // pack P^T -> sPT[q][kr], one 8B half4 write per c-tile
#pragma unroll
            for (int c = 0; c < 4; c++) {
                half4v p = {(_Float16)sacc[t][c][0], (_Float16)sacc[t][c][1],
                            (_Float16)sacc[t][c][2], (_Float16)sacc[t][c][3]};
                *(half4v*)&sPT[wave][(t * 16 + l16) * 72 + c * 16 + quad * 4] = p;
            }
        }

        // PV: O^T += V^T P^T. A = V^T (m=d), B = P (n=q) from sPT.
#pragma unroll
        for (int kk = 0; kk < 2; kk++) {
            half8 pf0 = *(const half8*)&sPT[wave][(l16) * 72 + kk * 32 + quad * 8];
            half8 pf1 = *(const half8*)&sPT[wave][(16 + l16) * 72 + kk * 32 + quad * 8];
#pragma unroll
            for (int dt = 0; dt < 4; dt++) {
                half8 vf = *(const half8*)&sVT[(dt * 16 + l16) * 72 + kk * 32 + quad * 8];
                o[0][dt] = mfma16(vf, pf0, o[0][dt]);
                o[1][dt] = mfma16(vf, pf1, o[1][dt]);
            }
        }
    }

    // epilogue: normalize, per-wave LDS transpose (O^T -> O), coalesced 16B stores
#pragma unroll
    for (int t = 0; t < 2; t++) {
        float inv = 1.f / l_[t];
#pragma unroll
        for (int dt = 0; dt < 4; dt++) {
            floatx4 v = o[t][dt];
            half4v a = {(_Float16)(v[0] * inv), (_Float16)(v[1] * inv),
                        (_Float16)(v[2] * inv), (_Float16)(v[3] * inv)};
            *(half4v*)&sPT[wave][(t * 16 + l16) * 72 + dt * 16 + quad * 4] = a;
        }
    }
    __syncthreads();
#pragma unroll
    for (int i = 0; i < 4; i++) {
        int ql = i * 8 + (lane >> 3);
        int c8 = (lane & 7) * 8;
        half8 vv = *(const half8*)&sPT[wave][ql * 72 + c8];
        *(half8*)(out + (long)(b * 1024 + n0 + wave * 32 + ql) * 1024 + h * 64 + c8) = vv;
    }
}

// ---------------- launch ----------------
extern "C" void kernel_launch(void* const* d_in, const int* in_sizes, int n_in,
                              void* d_out, int out_size, void* d_ws, size_t ws_size,
                              hipStream_t stream) {
    const float* x      = (const float*)d_in[0];
    const float* w_qkv  = (const float*)d_in[1];
    const float* w_proj = (const float*)d_in[2];
    const float* b_proj = (const float*)d_in[3];

    char* ws = (char*)d_ws;
    _Float16* qkh    = (_Float16*)ws;                      // 32MB [8192][2048] (Q|K)
    _Float16* vT     = (_Float16*)(ws + 33554432);         // 16MB [128*64][1024] (V^T)
    _Float16* xh     = (_Float16*)(ws + 50331648);         // 16MB [8192][1024]; attnh alias
    _Float16* wqkvh  = (_Float16*)(ws + 67108864);         // 6MB [3072][1024]
    _Float16* wprojh = (_Float16*)(ws + 73400320);         // 2MB [1024][1024]
    _Float16* attnh  = xh;                                 // flash out (xh dead after GEMM1)

    cvt_all<<<12288, 256, 0, stream>>>(x, w_qkv, w_proj, xh, wqkvh, wprojh);

    // QKV GEMM (reg-staged 128², 5 blocks/CU): cols 0..2047 -> qkh, 2048+ -> vT^T
    gemm_tn<true><<<dim3(64, 24), 256, 0, stream>>>(xh, wqkvh, qkh, 2048, vT, 2048,
                                                    nullptr, nullptr, 8192, 3072, 1024);
    flash_attn<<<dim3(128, 8), 256, 0, stream>>>(qkh, vT, attnh);
    // proj GEMM (1 exact generation @ 256x128): f32 + bias epilogue
    gemm256<<<dim3(32, 8), 512, 0, stream>>>(attnh, wprojh, nullptr, 0, nullptr, 1 << 30,
                                             (float*)d_out, b_proj, 1024, 1024);
}

// Round 8
// 240.499 us; speedup vs baseline: 2.1143x; 2.1143x over previous
//
#include <hip/hip_runtime.h>

typedef _Float16 half8 __attribute__((ext_vector_type(8)));
typedef _Float16 half4v __attribute__((ext_vector_type(4)));
typedef float floatx4 __attribute__((ext_vector_type(4)));

#define AS3 __attribute__((address_space(3)))
#define AS1 __attribute__((address_space(1)))

// async global->LDS, 16B per lane, wave-uniform LDS base + lane*16
__device__ __forceinline__ void gload_lds16(const _Float16* g, _Float16* l) {
    __builtin_amdgcn_global_load_lds((AS1 void*)g, (AS3 void*)l, 16, 0, 0);
}

__device__ __forceinline__ floatx4 mfma16(half8 a, half8 b, floatx4 c) {
    return __builtin_amdgcn_mfma_f32_16x16x32_f16(a, b, c, 0, 0, 0);
}

// ---------------- fused f32 -> f16 convert of all three inputs ----------------
// Separate pass is REQUIRED: fusing cvt into GEMM staging (R6) re-reads f32
// sources once per re-used panel -> 105MB fetch, MfmaUtil 19%, +35us. One
// pass amortizes conversion once (52MB read + 26MB write, ~16us).
__global__ __launch_bounds__(256) void cvt_all(const float* __restrict__ x,
                                               const float* __restrict__ wq,
                                               const float* __restrict__ wp,
                                               _Float16* __restrict__ xh,
                                               _Float16* __restrict__ wqh,
                                               _Float16* __restrict__ wph) {
    long i = (long)blockIdx.x * 256 + threadIdx.x;   // float4 index
    const float4* src; half4v* dst; long off;
    if (i < 2097152)      { src = (const float4*)x;  dst = (half4v*)xh;  off = i; }
    else if (i < 2883584) { src = (const float4*)wq; dst = (half4v*)wqh; off = i - 2097152; }
    else                  { src = (const float4*)wp; dst = (half4v*)wph; off = i - 2883584; }
    float4 v = src[off];
    half4v h = {(_Float16)v.x, (_Float16)v.y, (_Float16)v.z, (_Float16)v.w};
    dst[off] = h;
}

// ---------------- TN GEMM (QKV): reg-staged pipeline, 4 blocks/CU -----------
// C[M,N] = A[M,K] * B[N,K]^T. 128x128 tile, BK=32, 256 threads, dbuf LDS.
// Best-measured structure (71-73us QKV): global->VGPR right after barrier,
// compute from LDS, ds_write regs -> other buffer (vmcnt wait lands one
// compute phase after issue).
// STRUCTURAL PLATEAU, verified from three directions:
//  - schedules: gload_lds 74.6 (R1), 8-phase 256² 82.8 (R3), 256x128
//    triple-buf 76.9 (R4) — all neutral/worse than 71-73;
//  - fusion: f32-staged cvt-fused 107+ (R6, panel re-reads double traffic);
//  - occupancy: __launch_bounds__(256,5) forces 48-VGPR budget -> scratch
//    spill (WRITE_SIZE 52MB -> 1.07GB, 350-440us, R7).  64 VGPR needs the
//    (256,4) bound; 4 blocks/CU IS the occupancy optimum for this footprint.
// LDS swizzle: chunk c of row r -> slot c ^ ((r>>1)&3) (involution; verified
// SQ_LDS_BANK_CONFLICT = 0).
__global__ __launch_bounds__(256, 4) void gemm_tn(
    const _Float16* __restrict__ A, const _Float16* __restrict__ B,
    _Float16* __restrict__ Ch, int ldc, _Float16* __restrict__ Vt, int split,
    float* __restrict__ Cf, const float* __restrict__ bias,
    int M, int Nn, int K)
{
    __shared__ _Float16 sA[2][128 * 32];
    __shared__ _Float16 sB[2][128 * 32];
    const int tid  = threadIdx.x;
    const int lane = tid & 63, wave = tid >> 6;
    const int quad = lane >> 4, l16 = lane & 15;
    const int wr = wave >> 1, wc = wave & 1;
    const long m0 = (long)blockIdx.x * 128, n0 = (long)blockIdx.y * 128;

    // thread tid owns row srow (and srow+64), 16B chunk (tid&3) of the 64B k-row.
    const int srow = tid >> 2;
    const int sslot = ((tid & 3) ^ ((srow >> 1) & 3)) * 8;
    const int dlo = srow * 32 + sslot;
    const int dhi = (srow + 64) * 32 + sslot;
    const _Float16* gA0 = A + (m0 + srow) * (long)K + (tid & 3) * 8;
    const _Float16* gA1 = A + (m0 + srow + 64) * (long)K + (tid & 3) * 8;
    const _Float16* gB0 = B + (n0 + srow) * (long)K + (tid & 3) * 8;
    const _Float16* gB1 = B + (n0 + srow + 64) * (long)K + (tid & 3) * 8;

    const int swz = (l16 >> 1) & 3;
    const int aoff = ((quad ^ swz) * 8);

    floatx4 acc[4][4] = {};
    const int nk = K >> 5;

    // prologue: tile 0 -> VGPR -> LDS buf 0
    half8 rA0 = *(const half8*)gA0, rA1 = *(const half8*)gA1;
    half8 rB0 = *(const half8*)gB0, rB1 = *(const half8*)gB1;
    *(half8*)&sA[0][dlo] = rA0; *(half8*)&sA[0][dhi] = rA1;
    *(half8*)&sB[0][dlo] = rB0; *(half8*)&sB[0][dhi] = rB1;

    for (int kk = 0; kk < nk; kk++) {
        const int cur = kk & 1;
        __syncthreads();               // lgkm drain only; vmcnt already 0 here
        const bool more = (kk + 1 < nk);
        if (more) {
            const long k0 = (long)(kk + 1) << 5;
            rA0 = *(const half8*)(gA0 + k0); rA1 = *(const half8*)(gA1 + k0);
            rB0 = *(const half8*)(gB0 + k0); rB1 = *(const half8*)(gB1 + k0);
        }

        const _Float16* cA = &sA[cur][0];
        const _Float16* cB = &sB[cur][0];
        half8 af[4], bf[4];
#pragma unroll
        for (int t = 0; t < 4; t++)
            af[t] = *(const half8*)&cA[(wr * 64 + t * 16 + l16) * 32 + aoff];
#pragma unroll
        for (int t = 0; t < 4; t++)
            bf[t] = *(const half8*)&cB[(wc * 64 + t * 16 + l16) * 32 + aoff];
#pragma unroll
        for (int tm = 0; tm < 4; tm++)
#pragma unroll
            for (int tn = 0; tn < 4; tn++)
                acc[tm][tn] = mfma16(af[tm], bf[tn], acc[tm][tn]);

        if (more) {
            _Float16* nA = &sA[cur ^ 1][0];
            _Float16* nB = &sB[cur ^ 1][0];
            *(half8*)&nA[dlo] = rA0; *(half8*)&nA[dhi] = rA1;   // vmcnt wait lands here,
            *(half8*)&nB[dlo] = rB0; *(half8*)&nB[dhi] = rB1;   // one compute phase after issue
        }
    }

    // epilogue: C/D layout col=lane&15, row=quad*4+reg (verified m89/m91)
#pragma unroll
    for (int tm = 0; tm < 4; tm++) {
        long row = m0 + wr * 64 + tm * 16 + quad * 4;
#pragma unroll
        for (int tn = 0; tn < 4; tn++) {
            long col = n0 + wc * 64 + tn * 16 + l16;
            if (Cf) {
                float bv = bias ? bias[col] : 0.f;
#pragma unroll
                for (int r = 0; r < 4; r++)
                    Cf[(row + r) * (long)Nn + col] = acc[tm][tn][r] + bv;
            } else if (col >= split) {
                // transposed V write: Vt[(b*16+h)*64+d][n], n = 4 consecutive rows
                long cv = col - split;
                long vrow = ((row >> 10) * 16 + (cv >> 6)) * 64 + (cv & 63);
                long nn = row & 1023;
                half4v pv = {(_Float16)acc[tm][tn][0], (_Float16)acc[tm][tn][1],
                             (_Float16)acc[tm][tn][2], (_Float16)acc[tm][tn][3]};
                *(half4v*)&Vt[vrow * 1024 + nn] = pv;
            } else {
#pragma unroll
                for (int r = 0; r < 4; r++)
                    Ch[(row + r) * (long)ldc + col] = (_Float16)acc[tm][tn][r];
            }
        }
    }
}

// ---------------- 256x128 triple-buffered counted-vmcnt TN GEMM (proj) ------
// Kept ONLY for proj: grid 32x8 = 256 blocks = exactly 1 generation @ 1
// block/CU -> ~25-28us (vs gemm_tn's ~34 at 512 blocks).
__global__ __launch_bounds__(512, 2) void gemm256(
    const _Float16* __restrict__ A, const _Float16* __restrict__ B,
    _Float16* __restrict__ Ch, int ldc, _Float16* __restrict__ Vt, int split,
    float* __restrict__ Cf, const float* __restrict__ bias, int Nn, int K)
{
    __shared__ _Float16 sAB[3 * 24576];   // [buf][ A:16384 | B:8192 ] halfs

    const int nwg = gridDim.x * gridDim.y;
    int bid = blockIdx.y * gridDim.x + blockIdx.x;
    const int cpx = nwg >> 3;
    bid = (bid & 7) * cpx + (bid >> 3);
    const int gsz = gridDim.y << 3;
    const int bxg = bid / gsz;
    const int rem = bid - bxg * gsz;
    const int by = rem >> 3;
    const int bx = (bxg << 3) + (rem & 7);

    const int tid = threadIdx.x;
    const int lane = tid & 63, wave = tid >> 6;
    const int quad = lane >> 4, l16 = lane & 15;
    const int wm = wave >> 1, wn = wave & 1;      // 4M x 2N wave grid
    const long m0 = (long)bx * 256, n0 = (long)by * 128;

    const int gch = ((tid & 7) ^ ((tid >> 3) & 7)) * 8;
    const _Float16* gA = A + (m0 + (tid >> 3)) * (long)K + gch;
    const _Float16* gB = B + (n0 + (tid >> 3)) * (long)K + gch;
    const int wst = wave * 512;

#define STAGE(sb, u) do {                                                     \
    const long ko = (long)(u) * 64;                                           \
    _Float16* d = &sAB[(sb) * 24576];                                         \
    gload_lds16(gA + ko,                 d + wst);                            \
    gload_lds16(gA +  64 * (long)K + ko, d + 4096  + wst);                    \
    gload_lds16(gA + 128 * (long)K + ko, d + 8192  + wst);                    \
    gload_lds16(gA + 192 * (long)K + ko, d + 12288 + wst);                    \
    gload_lds16(gB + ko,                 d + 16384 + wst);                    \
    gload_lds16(gB +  64 * (long)K + ko, d + 20480 + wst);                    \
} while (0)

    const int NT = K >> 6;
    STAGE(0, 0); STAGE(1, 1);
    asm volatile("s_waitcnt vmcnt(6)" ::: "memory");   // tile 0 resident
    __builtin_amdgcn_s_barrier();

    const int cs0 = (quad ^ (l16 & 7)) * 8;         // ks=0 swizzled chunk
    const int cs1 = ((4 + quad) ^ (l16 & 7)) * 8;   // ks=1

    floatx4 acc[4][4] = {};
    half8 afr[4][2], bf0[2][2], bf1[2][2];

    int cb = 0, sb = 2;   // cur buf = t%3, stage buf = (t+2)%3
    for (int t = 0; t < NT; ++t) {
        const _Float16* cA = &sAB[cb * 24576 + wm * 4096];
        const _Float16* cB = &sAB[cb * 24576 + 16384 + wn * 4096];

#pragma unroll
        for (int f = 0; f < 4; f++) {
            const _Float16* p = &cA[(f * 16 + l16) * 64];
            afr[f][0] = *(const half8*)&p[cs0];
            afr[f][1] = *(const half8*)&p[cs1];
        }
#pragma unroll
        for (int nf = 0; nf < 2; nf++) {
            const _Float16* p = &cB[(nf * 16 + l16) * 64];
            bf0[nf][0] = *(const half8*)&p[cs0];
            bf0[nf][1] = *(const half8*)&p[cs1];
        }
        if (t + 2 < NT) STAGE(sb, t + 2);
        __builtin_amdgcn_s_barrier();
        asm volatile("s_waitcnt lgkmcnt(0)" ::: "memory");
        __builtin_amdgcn_sched_barrier(0);
        __builtin_amdgcn_s_setprio(1);
#pragma unroll
        for (int f = 0; f < 4; f++)
#pragma unroll
            for (int nf = 0; nf < 2; nf++) {
                acc[f][nf] = mfma16(afr[f][0], bf0[nf][0], acc[f][nf]);
                acc[f][nf] = mfma16(afr[f][1], bf0[nf][1], acc[f][nf]);
            }
        __builtin_amdgcn_s_setprio(0);
        __builtin_amdgcn_s_barrier();

#pragma unroll
        for (int nf = 0; nf < 2; nf++) {
            const _Float16* p = &cB[((2 + nf) * 16 + l16) * 64];
            bf1[nf][0] = *(const half8*)&p[cs0];
            bf1[nf][1] = *(const half8*)&p[cs1];
        }
        __builtin_amdgcn_s_barrier();
        asm volatile("s_waitcnt lgkmcnt(0)" ::: "memory");
        __builtin_amdgcn_sched_barrier(0);
        __builtin_amdgcn_s_setprio(1);
#pragma unroll
        for (int f = 0; f < 4; f++)
#pragma unroll
            for (int nf = 0; nf < 2; nf++) {
                acc[f][2 + nf] = mfma16(afr[f][0], bf1[nf][0], acc[f][2 + nf]);
                acc[f][2 + nf] = mfma16(afr[f][1], bf1[nf][1], acc[f][2 + nf]);
            }
        __builtin_amdgcn_s_setprio(0);
        if (t + 2 < NT)       { asm volatile("s_waitcnt vmcnt(6)" ::: "memory"); }
        else if (t == NT - 2) { asm volatile("s_waitcnt vmcnt(0)" ::: "memory"); }
        __builtin_amdgcn_s_barrier();
        cb = (cb + 1 == 3) ? 0 : cb + 1;
        sb = (sb + 1 == 3) ? 0 : sb + 1;
    }
#undef STAGE

#pragma unroll
    for (int f = 0; f < 4; f++) {
        long row = m0 + wm * 64 + f * 16 + quad * 4;
#pragma unroll
        for (int cn = 0; cn < 4; cn++) {
            long col = n0 + wn * 64 + cn * 16 + l16;
            if (Cf) {
                float bv = bias ? bias[col] : 0.f;
#pragma unroll
                for (int r = 0; r < 4; r++)
                    Cf[(row + r) * (long)Nn + col] = acc[f][cn][r] + bv;
            } else if (col >= split) {
                long cv = col - split;
                long vrow = ((row >> 10) * 16 + (cv >> 6)) * 64 + (cv & 63);
                long nn = row & 1023;
                half4v pv = {(_Float16)acc[f][cn][0], (_Float16)acc[f][cn][1],
                             (_Float16)acc[f][cn][2], (_Float16)acc[f][cn][3]};
                *(half4v*)&Vt[vrow * 1024 + nn] = pv;
            } else {
#pragma unroll
                for (int r = 0; r < 4; r++)
                    Ch[(row + r) * (long)ldc + col] = (_Float16)acc[f][cn][r];
            }
        }
    }
}

// ---------------- flash attention (S^T orientation) ----------------
// T14 async-STAGE split (K/V tile kt+1 global->reg issued right after tile
// kt's LDS stores; vmcnt wait lands at next iter's ds_write, one compute
// phase later) + T13 defer-max (skip O/l rescale while tile max growth <= 8;
// P bounded by e^8, f16-safe) + SCALE folded into Q at load (0.125 = 2^-3,
// exact in f16).
__global__ __launch_bounds__(256, 4) void flash_attn(const _Float16* __restrict__ qk,
                                                     const _Float16* __restrict__ vt,
                                                     _Float16* __restrict__ out)
{
    const int bh = blockIdx.x, b = bh >> 4, h = bh & 15;
    const int n0 = blockIdx.y * 128;
    const int tid = threadIdx.x, lane = tid & 63, wave = tid >> 6;
    const int quad = lane >> 4, l16 = lane & 15;

    __shared__ _Float16 sK[64 * 72];        // [kr][d] pad 72
    __shared__ _Float16 sVT[64 * 72];       // [d][kr] pad 72
    __shared__ _Float16 sPT[4][32 * 72];    // per-wave P^T round-trip [q][kr], reused as sOut

    half8 qf[2][2];
    const _Float16* qbase = qk + (long)(b * 1024 + n0 + wave * 32) * 2048 + h * 64;
#pragma unroll
    for (int t = 0; t < 2; t++)
#pragma unroll
        for (int s = 0; s < 2; s++) {
            half8 v = *(const half8*)(qbase + (long)(t * 16 + l16) * 2048 + s * 32 + quad * 8);
#pragma unroll
            for (int j = 0; j < 8; j++) v[j] *= (_Float16)0.125f;   // exact pow2
            qf[t][s] = v;
        }

    const int srow = tid >> 3, scol8 = (tid & 7) * 8;
    const _Float16* kgb = qk + 1024 + h * 64 + scol8 + (long)(b * 1024 + srow) * 2048;
    const _Float16* vgb = vt + (long)(bh * 64 + srow) * 1024 + scol8;

    float m_[2] = {-1e30f, -1e30f}, l_[2] = {0.f, 0.f};
    floatx4 o[2][4] = {};

    // T14 prologue: tile 0 -> regs
    half8 rK0 = *(const half8*)(kgb);
    half8 rK1 = *(const half8*)(kgb + (long)32 * 2048);
    half8 rV0 = *(const half8*)(vgb);
    half8 rV1 = *(const half8*)(vgb + (long)32 * 1024);

    for (int kt = 0; kt < 16; kt++) {
        __syncthreads();                       // prev tile's LDS readers done
        *(half8*)&sK[srow * 72 + scol8]          = rK0;
        *(half8*)&sK[(srow + 32) * 72 + scol8]   = rK1;
        *(half8*)&sVT[srow * 72 + scol8]         = rV0;
        *(half8*)&sVT[(srow + 32) * 72 + scol8]  = rV1;
        __syncthreads();

        if (kt + 1 < 16) {                     // issue kt+1 loads; waited at
            const long kr0n = (long)(kt + 1) * 64;          // next iter's stores
            rK0 = *(const half8*)(kgb + kr0n * 2048);
            rK1 = *(const half8*)(kgb + (kr0n + 32) * 2048);
            rV0 = *(const half8*)(vgb + kr0n);
            rV1 = *(const half8*)(vgb + (long)32 * 1024 + kr0n);
        }

        // S^T = K Q^T: A=K (m=kr), B=Q (n=q). C-layout: kr=c*16+quad*4+r, q=t*16+l16
        floatx4 sacc[2][4] = {};
#pragma unroll
        for (int c = 0; c < 4; c++)
#pragma unroll
            for (int s = 0; s < 2; s++) {
                half8 kf = *(const half8*)&sK[(c * 16 + l16) * 72 + s * 32 + quad * 8];
                sacc[0][c] = mfma16(kf, qf[0][s], sacc[0][c]);
                sacc[1][c] = mfma16(kf, qf[1][s], sacc[1][c]);
            }

        // online softmax over kr: in-lane reduce + 2 shuffles (xor16, xor32)
#pragma unroll
        for (int t = 0; t < 2; t++) {
            float mx = -1e30f;
#pragma unroll
            for (int c = 0; c < 4; c++)
#pragma unroll
                for (int r = 0; r < 4; r++)
                    mx = fmaxf(mx, sacc[t][c][r]);
            mx = fmaxf(mx, __shfl_xor(mx, 16));
            mx = fmaxf(mx, __shfl_xor(mx, 32));
            // T13 defer-max: only rescale when max grew past threshold
            if (__any(mx > m_[t] + 8.f)) {
                float mn = fmaxf(m_[t], mx);
                float al = __expf(m_[t] - mn);
                m_[t] = mn;
                l_[t] *= al;
#pragma unroll
                for (int dt = 0; dt < 4; dt++) o[t][dt] *= al;
            }
            float rs = 0.f;
#pragma unroll
            for (int c = 0; c < 4; c++)
#pragma unroll
                for (int r = 0; r < 4; r++) {
                    float p = __expf(sacc[t][c][r] - m_[t]);
                    sacc[t][c][r] = p;
                    rs += p;
                }
            rs += __shfl_xor(rs, 16);
            rs += __shfl_xor(rs, 32);
            l_[t] += rs;
            // pack P^T -> sPT[q][kr], one 8B half4 write per c-tile
#pragma unroll
            for (int c = 0; c < 4; c++) {
                half4v p = {(_Float16)sacc[t][c][0], (_Float16)sacc[t][c][1],
                            (_Float16)sacc[t][c][2], (_Float16)sacc[t][c][3]};
                *(half4v*)&sPT[wave][(t * 16 + l16) * 72 + c * 16 + quad * 4] = p;
            }
        }

        // PV: O^T += V^T P^T. A = V^T (m=d), B = P (n=q) from sPT.
#pragma unroll
        for (int kk = 0; kk < 2; kk++) {
            half8 pf0 = *(const half8*)&sPT[wave][(l16) * 72 + kk * 32 + quad * 8];
            half8 pf1 = *(const half8*)&sPT[wave][(16 + l16) * 72 + kk * 32 + quad * 8];
#pragma unroll
            for (int dt = 0; dt < 4; dt++) {
                half8 vf = *(const half8*)&sVT[(dt * 16 + l16) * 72 + kk * 32 + quad * 8];
                o[0][dt] = mfma16(vf, pf0, o[0][dt]);
                o[1][dt] = mfma16(vf, pf1, o[1][dt]);
            }
        }
    }

    // epilogue: normalize, per-wave LDS transpose (O^T -> O), coalesced 16B stores
#pragma unroll
    for (int t = 0; t < 2; t++) {
        float inv = 1.f / l_[t];
#pragma unroll
        for (int dt = 0; dt < 4; dt++) {
            floatx4 v = o[t][dt];
            half4v a = {(_Float16)(v[0] * inv), (_Float16)(v[1] * inv),
                        (_Float16)(v[2] * inv), (_Float16)(v[3] * inv)};
            *(half4v*)&sPT[wave][(t * 16 + l16) * 72 + dt * 16 + quad * 4] = a;
        }
    }
    __syncthreads();
#pragma unroll
    for (int i = 0; i < 4; i++) {
        int ql = i * 8 + (lane >> 3);
        int c8 = (lane & 7) * 8;
        half8 vv = *(const half8*)&sPT[wave][ql * 72 + c8];
        *(half8*)(out + (long)(b * 1024 + n0 + wave * 32 + ql) * 1024 + h * 64 + c8) = vv;
    }
}

// ---------------- launch ----------------
extern "C" void kernel_launch(void* const* d_in, const int* in_sizes, int n_in,
                              void* d_out, int out_size, void* d_ws, size_t ws_size,
                              hipStream_t stream) {
    const float* x      = (const float*)d_in[0];
    const float* w_qkv  = (const float*)d_in[1];
    const float* w_proj = (const float*)d_in[2];
    const float* b_proj = (const float*)d_in[3];

    char* ws = (char*)d_ws;
    _Float16* qkh    = (_Float16*)ws;                      // 32MB [8192][2048] (Q|K)
    _Float16* vT     = (_Float16*)(ws + 33554432);         // 16MB [128*64][1024] (V^T)
    _Float16* xh     = (_Float16*)(ws + 50331648);         // 16MB [8192][1024]; attnh alias
    _Float16* wqkvh  = (_Float16*)(ws + 67108864);         // 6MB [3072][1024]
    _Float16* wprojh = (_Float16*)(ws + 73400320);         // 2MB [1024][1024]
    _Float16* attnh  = xh;                                 // flash out (xh dead after GEMM1)

    cvt_all<<<12288, 256, 0, stream>>>(x, w_qkv, w_proj, xh, wqkvh, wprojh);

    // QKV GEMM (reg-staged 128², 4 blocks/CU): cols 0..2047 -> qkh, 2048+ -> vT^T
    gemm_tn<<<dim3(64, 24), 256, 0, stream>>>(xh, wqkvh, qkh, 2048, vT, 2048,
                                              nullptr, nullptr, 8192, 3072, 1024);
    flash_attn<<<dim3(128, 8), 256, 0, stream>>>(qkh, vT, attnh);
    // proj GEMM (1 exact generation @ 256x128): f32 + bias epilogue
    gemm256<<<dim3(32, 8), 512, 0, stream>>>(attnh, wprojh, nullptr, 0, nullptr, 1 << 30,
                                             (float*)d_out, b_proj, 1024, 1024);
}